// Round 2
// baseline (1194.688 us; speedup 1.0000x reference)
//
#include <hip/hip_runtime.h>
#include <math.h>

#define T_DIM 1000
#define C_DIM 500
#define U_DIM 100
#define NEGINF (-INFINITY)

__device__ __forceinline__ float lse2f(float a, float b) {
    float m = fmaxf(a, b);
    if (m == NEGINF) return NEGINF;
    float mn = fminf(a, b);
    return m + __logf(1.0f + __expf(mn - m));
}

__device__ __forceinline__ float lse3f(float x1, float x2, float x3) {
    float m = fmaxf(fmaxf(x1, x2), x3);
    if (m == NEGINF) return NEGINF;
    return m + __logf(__expf(x1 - m) + __expf(x2 - m) + __expf(x3 - m));
}

// Bug-compatible replica of reference _log_sub_exp (incl. inf-substitution quirk).
__device__ __forceinline__ float log_sub_expf(float a, float b) {
    bool ia = isinf(a), ib = isinf(b);
    if (!ia && !ib) {
        float ans = b + __logf(__expf(a - b) - 1.0f);
        if (isinf(ans)) ans = -2001.0f + __logf(__expf(1.0f) - 1.0f);
        return ans;
    }
    if (!ia && ib) return a;
    return NEGINF;
}

// ---------------- forward scan: one wave64, 4 states/lane, no barriers -------
__device__ __forceinline__ void fwd_scan(const float* __restrict__ base,
                                         const int* __restrict__ ysb,
                                         int hl, int yl,
                                         float* __restrict__ A)
{
    const int L = threadIdx.x & 63;
    const int s1 = 4 * L + 1, s3 = 4 * L + 3;
    const int u1 = 2 * L, u3 = 2 * L + 1;
    const int lab1 = ysb[min(u1, U_DIM - 1)];
    const int lab3 = ysb[min(u3, U_DIM - 1)];
    const int labm = ysb[min(max(u1 - 1, 0), U_DIM - 1)];   // ys[2L-1]
    const bool skip1 = (s1 >= 3) && (lab1 != labm);
    const bool skip3 = (lab3 != lab1);                      // s3>=3 always
    const int ty = 2 * yl;
    const bool v0 = (4 * L     <= 200) && (4 * L     <= ty);
    const bool v1 = (s1        <= 200) && (s1        <= ty);
    const bool v2 = (4 * L + 2 <= 200) && (4 * L + 2 <= ty);
    const bool v3 = (s3        <= 200) && (s3        <= ty);
    const bool st = (L < 50);

    float a0 = (L == 0) ? 0.0f : NEGINF, a1 = NEGINF, a2 = NEGINF, a3 = NEGINF;

    float rb[4], r1[4], r3[4];                 // 4-deep prefetch ring
#pragma unroll
    for (int k = 0; k < 4; ++k) {
        const float* r = base + (size_t)k * C_DIM;
        rb[k] = r[0]; r1[k] = r[lab1]; r3[k] = r[lab3];
    }
    for (int tb = 0; tb < T_DIM; tb += 4) {
#pragma unroll
        for (int k = 0; k < 4; ++k) {
            const int t = tb + k;
            float p0 = v0 ? rb[k] : NEGINF;
            float p1 = v1 ? r1[k] : NEGINF;
            float p2 = v2 ? rb[k] : NEGINF;
            float p3 = v3 ? r3[k] : NEGINF;
            if (t + 4 < T_DIM) {
                const float* r = base + (size_t)(t + 4) * C_DIM;
                rb[k] = r[0]; r1[k] = r[lab1]; r3[k] = r[lab3];
            }
            float am1 = __shfl_up(a3, 1, 64);  // a[4L-1]
            if (L == 0) am1 = NEGINF;
            float n0 = p0 + lse2f(a0, am1);
            float n1 = p1 + lse3f(a1, a0, skip1 ? am1 : NEGINF);
            float n2 = p2 + lse2f(a2, a1);
            float n3 = p3 + lse3f(a3, a2, skip3 ? a1 : NEGINF);
            a0 = n0; a1 = n1; a2 = n2; a3 = n3;
            if (st) {
                float* Ar = A + (size_t)t * U_DIM;
                bool live = (t < hl);
                Ar[u1] = live ? n1 : NEGINF;
                Ar[u3] = live ? n3 : NEGINF;
            }
        }
    }
}

// ------------- backward scan (store mode): writes raw b_l and Z -------------
__device__ __forceinline__ void bwd_scan_store(const float* __restrict__ base,
                                               const int* __restrict__ ysb,
                                               int hl, int yl,
                                               float* __restrict__ Braw,
                                               float* __restrict__ Z)
{
    const int L = threadIdx.x & 63;
    const int s0 = 4 * L, s1 = 4 * L + 1, s2 = 4 * L + 2, s3 = 4 * L + 3;
    const int u1 = 2 * L, u3 = 2 * L + 1;
    const int lab1 = ysb[min(u1, U_DIM - 1)];
    const int lab3 = ysb[min(u3, U_DIM - 1)];
    const int labn = ysb[min(u3 + 1, U_DIM - 1)];           // ys[2L+2]
    const bool skipA = (s1 < 199) && (lab3 != lab1);        // allow_skip_n2[s1]
    const bool skipB = (s3 < 199) && (labn != lab3);        // allow_skip_n2[s3]
    const int ty = 2 * yl;
    const bool v0 = (s0 <= 200) && (s0 <= ty);
    const bool v1 = (s1 <= 200) && (s1 <= ty);
    const bool v2 = (s2 <= 200) && (s2 <= ty);
    const bool v3 = (s3 <= 200) && (s3 <= ty);
    const bool st = (L < 50);
    const float f0 = (s0 == ty || s0 == ty - 1) ? 0.0f : NEGINF;
    const float f1 = (s1 == ty || s1 == ty - 1) ? 0.0f : NEGINF;
    const float f2 = (s2 == ty || s2 == ty - 1) ? 0.0f : NEGINF;
    const float f3 = (s3 == ty || s3 == ty - 1) ? 0.0f : NEGINF;

    float b0 = NEGINF, b1 = NEGINF, b2 = NEGINF, b3 = NEGINF;
    float prev1 = NEGINF, prev3 = NEGINF;   // raw b_l at t+1

    // ring slot k holds p row (t+1) for t with (999-t)&3 == k
    float rb[4], r1[4], r3[4];
    rb[0] = NEGINF; r1[0] = NEGINF; r3[0] = NEGINF;   // t=999 -> row 1000 -> -inf
#pragma unroll
    for (int k = 1; k < 4; ++k) {
        const float* r = base + (size_t)(T_DIM - k) * C_DIM;
        rb[k] = r[0]; r1[k] = r[lab1]; r3[k] = r[lab3];
    }
    for (int ob = 0; ob < T_DIM; ob += 4) {
#pragma unroll
        for (int k = 0; k < 4; ++k) {
            const int t = T_DIM - 1 - ob - k;
            float ph0 = v0 ? rb[k] : NEGINF;   // p_ext[t+1][s]
            float ph1 = v1 ? r1[k] : NEGINF;
            float ph2 = v2 ? rb[k] : NEGINF;
            float ph3 = v3 ? r3[k] : NEGINF;
            if (t - 3 >= 1) {                  // refill for use at t-4 (row t-3)
                const float* r = base + (size_t)(t - 3) * C_DIM;
                rb[k] = r[0]; r1[k] = r[lab1]; r3[k] = r[lab3];
            }
            float q0 = ph0 + b0, q1 = ph1 + b1, q2 = ph2 + b2, q3 = ph3 + b3;
            float qd0 = __shfl_down(q0, 1, 64);   // q[4L+4]
            float qd1 = __shfl_down(q1, 1, 64);   // q[4L+5]
            if (L == 63) { qd0 = NEGINF; qd1 = NEGINF; }
            float n0 = lse2f(q0, q1);
            float n1 = lse3f(q1, q2, skipA ? q3 : NEGINF);
            float n2 = lse2f(q2, q3);
            float n3 = lse3f(q3, qd0, skipB ? qd1 : NEGINF);
            bool fin = (t == hl - 1);
            b0 = fin ? f0 : n0;
            b1 = fin ? f1 : n1;
            b2 = fin ? f2 : n2;
            b3 = fin ? f3 : n3;
            if (st) {
                float* Br = Braw + (size_t)t * U_DIM;
                float* Zr = Z    + (size_t)t * U_DIM;
                Br[u1] = b1;            Br[u3] = b3;
                Zr[u1] = prev1 + ph1;   Zr[u3] = prev3 + ph3;  // raw b[t+1]+p[t+1]
            }
            prev1 = b1; prev3 = b3;
        }
    }
}

// ------------------- fused: fwd wave + bwd wave + parallel loss -------------
extern "C" __global__ void __launch_bounds__(256)
brctc_fused(const float* __restrict__ nnet, const int* __restrict__ ys,
            const int* __restrict__ hlens, const int* __restrict__ ylens,
            float* A, float* Braw, float* Z, float* out)
{
    const int b = blockIdx.x;
    const int tid = threadIdx.x;
    const int wid = tid >> 6;
    const int hl = hlens[b], yl = ylens[b];
    const float* base = nnet + (size_t)b * T_DIM * C_DIM;
    const int* ysb = ys + b * U_DIM;
    float* Ab = A    + (size_t)b * T_DIM * U_DIM;
    float* Bb = Braw + (size_t)b * T_DIM * U_DIM;
    float* Zb = Z    + (size_t)b * T_DIM * U_DIM;

    if (wid == 0)      fwd_scan(base, ysb, hl, yl, Ab);
    else if (wid == 1) bwd_scan_store(base, ysb, hl, yl, Bb, Zb);
    __syncthreads();

    __shared__ float shm[2][U_DIM], shs[2][U_DIM], shlu[U_DIM];
    if (tid < 200) {
        const int u = (tid < 100) ? tid : tid - 100;
        const int h = (tid < 100) ? 0 : 1;
        const float inv_hl = 1.0f / (float)hl;
        const int t0 = h * (T_DIM / 2), t1 = t0 + (T_DIM / 2);
        float m = NEGINF, s = 0.0f;
        float a_next = Ab[(size_t)t0 * U_DIM + u];
        for (int t = t0; t < t1; ++t) {
            float a_t = a_next;
            a_next = (t + 1 < T_DIM) ? Ab[(size_t)(t + 1) * U_DIM + u] : NEGINF;
            float bl   = (a_t    == NEGINF) ? NEGINF : Bb[(size_t)t * U_DIM + u];
            float term = (a_next == NEGINF) ? NEGINF : Zb[(size_t)t * U_DIM + u];
            float bp = log_sub_expf(bl, term);
            float x = a_t + bp - 0.1f * (float)t * inv_hl;
            if (x != NEGINF) {
                float nm = fmaxf(m, x);
                s = s * __expf(m - nm) + __expf(x - nm);
                m = nm;
            }
        }
        shm[h][u] = m; shs[h][u] = s;
    }
    __syncthreads();
    if (tid < 100) {
        float m0 = shm[0][tid], m1 = shm[1][tid];
        float s0 = shs[0][tid], s1 = shs[1][tid];
        float M = fmaxf(m0, m1);
        float lu = NEGINF;
        if (M != NEGINF)
            lu = M + __logf(s0 * __expf(m0 - M) + s1 * __expf(m1 - M));
        shlu[tid] = lu;
    }
    __syncthreads();
    if (tid == 0) {
        int cnt = 0;
        for (int u = 0; u < U_DIM; ++u) cnt += (shlu[u] != NEGINF) ? 1 : 0;
        int last = cnt - 1;
        last = last < 0 ? 0 : (last > U_DIM - 1 ? U_DIM - 1 : last);
        out[b] = -shlu[last];
    }
}

// ---------------- fallback (small ws): serialized, still barrier-free -------
extern "C" __global__ void __launch_bounds__(64)
brctc_fwd64(const float* __restrict__ nnet, const int* __restrict__ ys,
            const int* __restrict__ hlens, const int* __restrict__ ylens, float* A)
{
    const int b = blockIdx.x;
    fwd_scan(nnet + (size_t)b * T_DIM * C_DIM, ys + b * U_DIM,
             hlens[b], ylens[b], A + (size_t)b * T_DIM * U_DIM);
}

extern "C" __global__ void __launch_bounds__(64)
brctc_bwd64(const float* __restrict__ nnet, const int* __restrict__ ys,
            const int* __restrict__ hlens, const int* __restrict__ ylens,
            const float* __restrict__ A, float* out)
{
    const int b = blockIdx.x;
    const int L = threadIdx.x & 63;
    const int s0 = 4 * L, s1 = 4 * L + 1, s2 = 4 * L + 2, s3 = 4 * L + 3;
    const int u1 = 2 * L, u3 = 2 * L + 1;
    const int hl = hlens[b], yl = ylens[b];
    const float* base = nnet + (size_t)b * T_DIM * C_DIM;
    const int* ysb = ys + b * U_DIM;
    const float* Ab = A + (size_t)b * T_DIM * U_DIM;
    const int lab1 = ysb[min(u1, U_DIM - 1)];
    const int lab3 = ysb[min(u3, U_DIM - 1)];
    const int labn = ysb[min(u3 + 1, U_DIM - 1)];
    const bool skipA = (s1 < 199) && (lab3 != lab1);
    const bool skipB = (s3 < 199) && (labn != lab3);
    const int ty = 2 * yl;
    const bool v0 = (s0 <= 200) && (s0 <= ty);
    const bool v1 = (s1 <= 200) && (s1 <= ty);
    const bool v2 = (s2 <= 200) && (s2 <= ty);
    const bool v3 = (s3 <= 200) && (s3 <= ty);
    const bool st = (L < 50);
    const float f0 = (s0 == ty || s0 == ty - 1) ? 0.0f : NEGINF;
    const float f1 = (s1 == ty || s1 == ty - 1) ? 0.0f : NEGINF;
    const float f2 = (s2 == ty || s2 == ty - 1) ? 0.0f : NEGINF;
    const float f3 = (s3 == ty || s3 == ty - 1) ? 0.0f : NEGINF;
    const float inv_hl = 1.0f / (float)hl;

    float b0 = NEGINF, b1 = NEGINF, b2 = NEGINF, b3 = NEGINF;
    float prev1 = NEGINF, prev3 = NEGINF;       // masked b_l at t+1
    float m1 = NEGINF, ss1 = 0.0f, m3 = NEGINF, ss3 = 0.0f;

    float rb[4], r1[4], r3[4], ra1[4], ra3[4];
    rb[0] = NEGINF; r1[0] = NEGINF; r3[0] = NEGINF;
#pragma unroll
    for (int k = 1; k < 4; ++k) {
        const float* r = base + (size_t)(T_DIM - k) * C_DIM;
        rb[k] = r[0]; r1[k] = r[lab1]; r3[k] = r[lab3];
    }
#pragma unroll
    for (int k = 0; k < 4; ++k) {
        if (st) {
            ra1[k] = Ab[(size_t)(T_DIM - 1 - k) * U_DIM + u1];
            ra3[k] = Ab[(size_t)(T_DIM - 1 - k) * U_DIM + u3];
        } else { ra1[k] = NEGINF; ra3[k] = NEGINF; }
    }
    for (int ob = 0; ob < T_DIM; ob += 4) {
#pragma unroll
        for (int k = 0; k < 4; ++k) {
            const int t = T_DIM - 1 - ob - k;
            float ph0 = v0 ? rb[k] : NEGINF;
            float ph1 = v1 ? r1[k] : NEGINF;
            float ph2 = v2 ? rb[k] : NEGINF;
            float ph3 = v3 ? r3[k] : NEGINF;
            float a1v = ra1[k], a3v = ra3[k];
            if (t - 3 >= 1) {
                const float* r = base + (size_t)(t - 3) * C_DIM;
                rb[k] = r[0]; r1[k] = r[lab1]; r3[k] = r[lab3];
            }
            if (t - 4 >= 0 && st) {
                ra1[k] = Ab[(size_t)(t - 4) * U_DIM + u1];
                ra3[k] = Ab[(size_t)(t - 4) * U_DIM + u3];
            }
            float q0 = ph0 + b0, q1 = ph1 + b1, q2 = ph2 + b2, q3 = ph3 + b3;
            float qd0 = __shfl_down(q0, 1, 64);
            float qd1 = __shfl_down(q1, 1, 64);
            if (L == 63) { qd0 = NEGINF; qd1 = NEGINF; }
            float n0 = lse2f(q0, q1);
            float n1 = lse3f(q1, q2, skipA ? q3 : NEGINF);
            float n2 = lse2f(q2, q3);
            float n3 = lse3f(q3, qd0, skipB ? qd1 : NEGINF);
            bool fin = (t == hl - 1);
            b0 = fin ? f0 : n0;
            b1 = fin ? f1 : n1;
            b2 = fin ? f2 : n2;
            b3 = fin ? f3 : n3;
            if (st) {
                float risk = 0.1f * (float)t * inv_hl;
                float bl1 = (a1v == NEGINF) ? NEGINF : b1;
                float bp1 = log_sub_expf(bl1, prev1 + ph1);
                float x1 = a1v + bp1 - risk;
                if (x1 != NEGINF) {
                    float nm = fmaxf(m1, x1);
                    ss1 = ss1 * __expf(m1 - nm) + __expf(x1 - nm);
                    m1 = nm;
                }
                prev1 = bl1;
                float bl3 = (a3v == NEGINF) ? NEGINF : b3;
                float bp3 = log_sub_expf(bl3, prev3 + ph3);
                float x3 = a3v + bp3 - risk;
                if (x3 != NEGINF) {
                    float nm = fmaxf(m3, x3);
                    ss3 = ss3 * __expf(m3 - nm) + __expf(x3 - nm);
                    m3 = nm;
                }
                prev3 = bl3;
            }
        }
    }
    __shared__ float shlu[U_DIM];
    if (st) {
        shlu[u1] = (m1 == NEGINF) ? NEGINF : (m1 + __logf(ss1));
        shlu[u3] = (m3 == NEGINF) ? NEGINF : (m3 + __logf(ss3));
    }
    __syncthreads();
    if (threadIdx.x == 0) {
        int cnt = 0;
        for (int u = 0; u < U_DIM; ++u) cnt += (shlu[u] != NEGINF) ? 1 : 0;
        int last = cnt - 1;
        last = last < 0 ? 0 : (last > U_DIM - 1 ? U_DIM - 1 : last);
        out[b] = -shlu[last];
    }
}

extern "C" void kernel_launch(void* const* d_in, const int* in_sizes, int n_in,
                              void* d_out, int out_size, void* d_ws, size_t ws_size,
                              hipStream_t stream) {
    const float* nnet  = (const float*)d_in[0];
    const int*   ys    = (const int*)d_in[1];
    const int*   hlens = (const int*)d_in[2];
    const int*   ylens = (const int*)d_in[3];
    float*       outp  = (float*)d_out;
    const int B = in_sizes[2];
    const size_t BTU = (size_t)B * T_DIM * U_DIM;

    if (ws_size >= 3 * BTU * sizeof(float)) {
        float* A    = (float*)d_ws;
        float* Braw = A + BTU;
        float* Z    = Braw + BTU;
        brctc_fused<<<B, 256, 0, stream>>>(nnet, ys, hlens, ylens, A, Braw, Z, outp);
    } else {
        float* A = (float*)d_ws;
        brctc_fwd64<<<B, 64, 0, stream>>>(nnet, ys, hlens, ylens, A);
        brctc_bwd64<<<B, 64, 0, stream>>>(nnet, ys, hlens, ylens, A, outp);
    }
}

// Round 4
// 612.606 us; speedup vs baseline: 1.9502x; 1.9502x over previous
//
#include <hip/hip_runtime.h>
#include <math.h>

#define T_DIM 1000
#define C_DIM 500
#define U_DIM 100
#define PAD   16          // head/tail padding rows for P/PB (ring over-reads)
#define DEPTH 16          // scan prefetch ring depth
#define AROWS (T_DIM + 5) // A/Braw rows (loss ring reads to row T+4)
#define NEGINF (-INFINITY)

__device__ __forceinline__ float lse2f(float a, float b) {
    float m = fmaxf(a, b);
    if (m == NEGINF) return NEGINF;
    float mn = fminf(a, b);
    return m + __logf(1.0f + __expf(mn - m));
}

__device__ __forceinline__ float lse3f(float x1, float x2, float x3) {
    float m = fmaxf(fmaxf(x1, x2), x3);
    if (m == NEGINF) return NEGINF;
    return m + __logf(__expf(x1 - m) + __expf(x2 - m) + __expf(x3 - m));
}

// Bug-compatible replica of reference _log_sub_exp (incl. inf-substitution quirk).
__device__ __forceinline__ float log_sub_expf(float a, float b) {
    bool ia = isinf(a), ib = isinf(b);
    if (!ia && !ib) {
        float ans = b + __logf(__expf(a - b) - 1.0f);
        if (isinf(ans)) ans = -2001.0f + __logf(__expf(1.0f) - 1.0f);
        return ans;
    }
    if (!ia && ib) return a;
    return NEGINF;
}

// ---------- pre-gather: compact label/blank log-probs, fully parallel -------
extern "C" __global__ void __launch_bounds__(128)
brctc_gather(const float* __restrict__ nnet, const int* __restrict__ ys,
             float* __restrict__ P, float* __restrict__ PB)
{
    const int t = blockIdx.x;
    const int b = blockIdx.y;
    const int tid = threadIdx.x;
    const float* row = nnet + ((size_t)b * T_DIM + t) * C_DIM;
    const size_t TP = T_DIM + 2 * PAD;
    if (tid < U_DIM) {
        int lab = ys[b * U_DIM + tid];
        P[((size_t)b * TP + PAD + t) * U_DIM + tid] = row[lab];
    } else if (tid == U_DIM) {
        PB[(size_t)b * TP + PAD + t] = row[0];
    }
}

// ---------------- forward scan: one wave64, compact-P, 16-deep ring ---------
__device__ __forceinline__ void fwd_scan2(const float* __restrict__ Pb,
                                          const float* __restrict__ PBb,
                                          const int* __restrict__ ysb,
                                          int hl, int yl,
                                          float* __restrict__ Ab)
{
    const int L = threadIdx.x & 63;
    const int s1 = 4 * L + 1, s3 = 4 * L + 3;
    const int u1 = 2 * L;
    const int lab1 = ysb[min(u1, U_DIM - 1)];
    const int lab3 = ysb[min(u1 + 1, U_DIM - 1)];
    const int labm = ysb[min(max(u1 - 1, 0), U_DIM - 1)];
    const bool skip1 = (s1 >= 3) && (lab1 != labm);
    const bool skip3 = (lab3 != lab1);
    const int ty = 2 * yl;
    const bool v0 = (4 * L     <= 200) && (4 * L     <= ty);
    const bool v1 = (s1        <= 200) && (s1        <= ty);
    const bool v2 = (4 * L + 2 <= 200) && (4 * L + 2 <= ty);
    const bool v3 = (s3        <= 200) && (s3        <= ty);
    const bool st = (L < 50);

    float a0 = (L == 0) ? 0.0f : NEGINF, a1 = NEGINF, a2 = NEGINF, a3 = NEGINF;

    // slot k consumed at t with t&15 == k, holds p row t
    float2 rl[DEPTH]; float rpb[DEPTH];
#pragma unroll
    for (int k = 0; k < DEPTH; ++k) {
        rl[k]  = ((const float2*)(Pb + (long)k * U_DIM))[L];
        rpb[k] = PBb[k];
    }
    auto step = [&](int t, int k) {
        float2 pl = rl[k]; float pbv = rpb[k];
        rl[k]  = ((const float2*)(Pb + (long)(t + DEPTH) * U_DIM))[L];
        rpb[k] = PBb[t + DEPTH];
        float p0 = v0 ? pbv : NEGINF;
        float p1 = v1 ? pl.x : NEGINF;
        float p2 = v2 ? pbv : NEGINF;
        float p3 = v3 ? pl.y : NEGINF;
        float am1 = __shfl_up(a3, 1, 64);
        if (L == 0) am1 = NEGINF;
        float n0 = p0 + lse2f(a0, am1);
        float n1 = p1 + lse3f(a1, a0, skip1 ? am1 : NEGINF);
        float n2 = p2 + lse2f(a2, a1);
        float n3 = p3 + lse3f(a3, a2, skip3 ? a1 : NEGINF);
        a0 = n0; a1 = n1; a2 = n2; a3 = n3;
        if (st) {
            bool live = (t < hl);
            ((float2*)(Ab + (size_t)t * U_DIM))[L] =
                make_float2(live ? n1 : NEGINF, live ? n3 : NEGINF);
        }
    };
    for (int tb = 0; tb < 992; tb += DEPTH) {
#pragma unroll
        for (int k = 0; k < DEPTH; ++k) step(tb + k, k);
    }
#pragma unroll
    for (int k = 0; k < 8; ++k) step(992 + k, k);
    // sentinel row T = -inf (consumed as a_next at t = T-1 in loss phase)
    if (st) ((float2*)(Ab + (size_t)T_DIM * U_DIM))[L] = make_float2(NEGINF, NEGINF);
}

// ---------------- backward scan: compact-P, stores raw b_l ------------------
__device__ __forceinline__ void bwd_scan2(const float* __restrict__ Pb,
                                          const float* __restrict__ PBb,
                                          const int* __restrict__ ysb,
                                          int hl, int yl,
                                          float* __restrict__ Bb)
{
    const int L = threadIdx.x & 63;
    const int s0 = 4 * L, s1 = 4 * L + 1, s2 = 4 * L + 2, s3 = 4 * L + 3;
    const int u1 = 2 * L;
    const int lab1 = ysb[min(u1, U_DIM - 1)];
    const int lab3 = ysb[min(u1 + 1, U_DIM - 1)];
    const int labn = ysb[min(u1 + 2, U_DIM - 1)];
    const bool skipA = (s1 < 199) && (lab3 != lab1);
    const bool skipB = (s3 < 199) && (labn != lab3);
    const int ty = 2 * yl;
    const bool v0 = (s0 <= 200) && (s0 <= ty);
    const bool v1 = (s1 <= 200) && (s1 <= ty);
    const bool v2 = (s2 <= 200) && (s2 <= ty);
    const bool v3 = (s3 <= 200) && (s3 <= ty);
    const bool st = (L < 50);
    const float f0 = (s0 == ty || s0 == ty - 1) ? 0.0f : NEGINF;
    const float f1 = (s1 == ty || s1 == ty - 1) ? 0.0f : NEGINF;
    const float f2 = (s2 == ty || s2 == ty - 1) ? 0.0f : NEGINF;
    const float f3 = (s3 == ty || s3 == ty - 1) ? 0.0f : NEGINF;

    float b0 = NEGINF, b1 = NEGINF, b2 = NEGINF, b3 = NEGINF;

    // slot k consumed at t with (999-t)&15==k, holds p row t+1
    float2 rl[DEPTH]; float rpb[DEPTH];
    rl[0] = make_float2(NEGINF, NEGINF); rpb[0] = NEGINF;   // row 1000 -> -inf
#pragma unroll
    for (int k = 1; k < DEPTH; ++k) {
        long row = T_DIM - k;
        rl[k]  = ((const float2*)(Pb + row * U_DIM))[L];
        rpb[k] = PBb[row];
    }
    auto step = [&](int t, int k) {
        float2 pl = rl[k]; float pbv = rpb[k];
        rl[k]  = ((const float2*)(Pb + (long)(t - (DEPTH - 1)) * U_DIM))[L];
        rpb[k] = PBb[t - (DEPTH - 1)];
        float ph0 = v0 ? pbv : NEGINF;   // p_ext[t+1]
        float ph1 = v1 ? pl.x : NEGINF;
        float ph2 = v2 ? pbv : NEGINF;
        float ph3 = v3 ? pl.y : NEGINF;
        float q0 = ph0 + b0, q1 = ph1 + b1, q2 = ph2 + b2, q3 = ph3 + b3;
        float qd0 = __shfl_down(q0, 1, 64);
        float qd1 = __shfl_down(q1, 1, 64);
        if (L == 63) { qd0 = NEGINF; qd1 = NEGINF; }
        float n0 = lse2f(q0, q1);
        float n1 = lse3f(q1, q2, skipA ? q3 : NEGINF);
        float n2 = lse2f(q2, q3);
        float n3 = lse3f(q3, qd0, skipB ? qd1 : NEGINF);
        bool fin = (t == hl - 1);
        b0 = fin ? f0 : n0;
        b1 = fin ? f1 : n1;
        b2 = fin ? f2 : n2;
        b3 = fin ? f3 : n3;
        if (st)
            ((float2*)(Bb + (size_t)t * U_DIM))[L] = make_float2(b1, b3);
    };
    for (int ob = 0; ob < 992; ob += DEPTH) {
#pragma unroll
        for (int k = 0; k < DEPTH; ++k) step(T_DIM - 1 - ob - k, k);
    }
#pragma unroll
    for (int k = 0; k < 8; ++k) step(7 - k, k);
}

// ------------------- fused: fwd wave + bwd wave + parallel loss -------------
extern "C" __global__ void __launch_bounds__(256)
brctc_fused(const float* __restrict__ P, const float* __restrict__ PB,
            const int* __restrict__ ys, const int* __restrict__ hlens,
            const int* __restrict__ ylens,
            float* __restrict__ A, float* __restrict__ Braw,
            float* __restrict__ out)
{
    const int b = blockIdx.x;
    const int tid = threadIdx.x;
    const int wid = tid >> 6;
    const int hl = hlens[b], yl = ylens[b];
    const size_t TP = T_DIM + 2 * PAD;
    const float* Pb  = P  + ((size_t)b * TP + PAD) * U_DIM;
    const float* PBb = PB + (size_t)b * TP + PAD;
    const int* ysb = ys + b * U_DIM;
    float* Ab = A    + (size_t)b * AROWS * U_DIM;
    float* Bb = Braw + (size_t)b * AROWS * U_DIM;

    if (wid == 0)      fwd_scan2(Pb, PBb, ysb, hl, yl, Ab);
    else if (wid == 1) bwd_scan2(Pb, PBb, ysb, hl, yl, Bb);
    __syncthreads();

    __shared__ float shm[2][U_DIM], shs[2][U_DIM], shlu[U_DIM];
    if (tid < 200) {
        const int u = (tid < 100) ? tid : tid - 100;
        const int h = (tid < 100) ? 0 : 1;
        const bool valu = (u < yl);               // p_l valid_s mask (s=2u+1<=2yl)
        const float inv_hl = 1.0f / (float)hl;
        const int t0 = h * 500;                   // t0 % 4 == 0
        float a_t    = Ab[(size_t)t0 * U_DIM + u];
        float braw_t = Bb[(size_t)t0 * U_DIM + u];
        // ring invariant: row r lives in slot (r - t0 - 1) & 3; consumed row
        // t+1 at slot (t - t0) & 3 == k; refill row t+5 -> same slot k.
        float ra[4], rbw[4], rp[4];
#pragma unroll
        for (int d = 0; d < 4; ++d) {
            long row = t0 + 1 + d;
            ra[d]  = Ab[row * U_DIM + u];
            rbw[d] = Bb[row * U_DIM + u];
            rp[d]  = valu ? Pb[row * U_DIM + u] : NEGINF;
        }
        float m = NEGINF, ssum = 0.0f;
        for (int tb = t0; tb < t0 + 500; tb += 4) {
#pragma unroll
            for (int k = 0; k < 4; ++k) {
                const int t = tb + k;
                const int slot = k;               // == (t - t0) & 3
                float a_nx = ra[slot], br_nx = rbw[slot], p_nx = rp[slot];
                long row = t + 5;                 // refill same slot
                ra[slot]  = Ab[row * U_DIM + u];
                rbw[slot] = Bb[row * U_DIM + u];
                rp[slot]  = valu ? Pb[row * U_DIM + u] : NEGINF;
                float bl   = (a_t  == NEGINF) ? NEGINF : braw_t;
                float term = (a_nx == NEGINF) ? NEGINF : (br_nx + p_nx);
                float bp = log_sub_expf(bl, term);
                float x = a_t + bp - 0.1f * (float)t * inv_hl;
                if (x != NEGINF) {
                    float nm = fmaxf(m, x);
                    ssum = ssum * __expf(m - nm) + __expf(x - nm);
                    m = nm;
                }
                a_t = a_nx; braw_t = br_nx;
            }
        }
        shm[h][u] = m; shs[h][u] = ssum;
    }
    __syncthreads();
    if (tid < 100) {
        float m0 = shm[0][tid], m1 = shm[1][tid];
        float s0 = shs[0][tid], s1 = shs[1][tid];
        float M = fmaxf(m0, m1);
        float lu = NEGINF;
        if (M != NEGINF)
            lu = M + __logf(s0 * __expf(m0 - M) + s1 * __expf(m1 - M));
        shlu[tid] = lu;
    }
    __syncthreads();
    if (tid == 0) {
        int cnt = 0;
        for (int u = 0; u < U_DIM; ++u) cnt += (shlu[u] != NEGINF) ? 1 : 0;
        int last = cnt - 1;
        last = last < 0 ? 0 : (last > U_DIM - 1 ? U_DIM - 1 : last);
        out[b] = -shlu[last];
    }
}

// =================== fallback (small ws): round-1-style direct path =========
__device__ __forceinline__ void fwd_scan_direct(const float* __restrict__ base,
                                                const int* __restrict__ ysb,
                                                int hl, int yl,
                                                float* __restrict__ A)
{
    const int L = threadIdx.x & 63;
    const int s1 = 4 * L + 1, s3 = 4 * L + 3;
    const int u1 = 2 * L, u3 = 2 * L + 1;
    const int lab1 = ysb[min(u1, U_DIM - 1)];
    const int lab3 = ysb[min(u3, U_DIM - 1)];
    const int labm = ysb[min(max(u1 - 1, 0), U_DIM - 1)];
    const bool skip1 = (s1 >= 3) && (lab1 != labm);
    const bool skip3 = (lab3 != lab1);
    const int ty = 2 * yl;
    const bool v0 = (4 * L     <= 200) && (4 * L     <= ty);
    const bool v1 = (s1        <= 200) && (s1        <= ty);
    const bool v2 = (4 * L + 2 <= 200) && (4 * L + 2 <= ty);
    const bool v3 = (s3        <= 200) && (s3        <= ty);
    const bool st = (L < 50);
    float a0 = (L == 0) ? 0.0f : NEGINF, a1 = NEGINF, a2 = NEGINF, a3 = NEGINF;
    float rb[4], r1[4], r3[4];
#pragma unroll
    for (int k = 0; k < 4; ++k) {
        const float* r = base + (size_t)k * C_DIM;
        rb[k] = r[0]; r1[k] = r[lab1]; r3[k] = r[lab3];
    }
    for (int tb = 0; tb < T_DIM; tb += 4) {
#pragma unroll
        for (int k = 0; k < 4; ++k) {
            const int t = tb + k;
            float p0 = v0 ? rb[k] : NEGINF;
            float p1 = v1 ? r1[k] : NEGINF;
            float p2 = v2 ? rb[k] : NEGINF;
            float p3 = v3 ? r3[k] : NEGINF;
            if (t + 4 < T_DIM) {
                const float* r = base + (size_t)(t + 4) * C_DIM;
                rb[k] = r[0]; r1[k] = r[lab1]; r3[k] = r[lab3];
            }
            float am1 = __shfl_up(a3, 1, 64);
            if (L == 0) am1 = NEGINF;
            float n0 = p0 + lse2f(a0, am1);
            float n1 = p1 + lse3f(a1, a0, skip1 ? am1 : NEGINF);
            float n2 = p2 + lse2f(a2, a1);
            float n3 = p3 + lse3f(a3, a2, skip3 ? a1 : NEGINF);
            a0 = n0; a1 = n1; a2 = n2; a3 = n3;
            if (st) {
                float* Ar = A + (size_t)t * U_DIM;
                bool live = (t < hl);
                Ar[u1] = live ? n1 : NEGINF;
                Ar[u3] = live ? n3 : NEGINF;
            }
        }
    }
}

extern "C" __global__ void __launch_bounds__(64)
brctc_fwd64(const float* __restrict__ nnet, const int* __restrict__ ys,
            const int* __restrict__ hlens, const int* __restrict__ ylens, float* A)
{
    const int b = blockIdx.x;
    fwd_scan_direct(nnet + (size_t)b * T_DIM * C_DIM, ys + b * U_DIM,
                    hlens[b], ylens[b], A + (size_t)b * T_DIM * U_DIM);
}

extern "C" __global__ void __launch_bounds__(64)
brctc_bwd64(const float* __restrict__ nnet, const int* __restrict__ ys,
            const int* __restrict__ hlens, const int* __restrict__ ylens,
            const float* __restrict__ A, float* out)
{
    const int b = blockIdx.x;
    const int L = threadIdx.x & 63;
    const int s0 = 4 * L, s1 = 4 * L + 1, s2 = 4 * L + 2, s3 = 4 * L + 3;
    const int u1 = 2 * L, u3 = 2 * L + 1;
    const int hl = hlens[b], yl = ylens[b];
    const float* base = nnet + (size_t)b * T_DIM * C_DIM;
    const int* ysb = ys + b * U_DIM;
    const float* Ab = A + (size_t)b * T_DIM * U_DIM;
    const int lab1 = ysb[min(u1, U_DIM - 1)];
    const int lab3 = ysb[min(u3, U_DIM - 1)];
    const int labn = ysb[min(u3 + 1, U_DIM - 1)];
    const bool skipA = (s1 < 199) && (lab3 != lab1);
    const bool skipB = (s3 < 199) && (labn != lab3);
    const int ty = 2 * yl;
    const bool v0 = (s0 <= 200) && (s0 <= ty);
    const bool v1 = (s1 <= 200) && (s1 <= ty);
    const bool v2 = (s2 <= 200) && (s2 <= ty);
    const bool v3 = (s3 <= 200) && (s3 <= ty);
    const bool st = (L < 50);
    const float f0 = (s0 == ty || s0 == ty - 1) ? 0.0f : NEGINF;
    const float f1 = (s1 == ty || s1 == ty - 1) ? 0.0f : NEGINF;
    const float f2 = (s2 == ty || s2 == ty - 1) ? 0.0f : NEGINF;
    const float f3 = (s3 == ty || s3 == ty - 1) ? 0.0f : NEGINF;
    const float inv_hl = 1.0f / (float)hl;

    float b0 = NEGINF, b1 = NEGINF, b2 = NEGINF, b3 = NEGINF;
    float prev1 = NEGINF, prev3 = NEGINF;
    float m1 = NEGINF, ss1 = 0.0f, m3 = NEGINF, ss3 = 0.0f;

    float rb[4], r1[4], r3[4], ra1[4], ra3[4];
    rb[0] = NEGINF; r1[0] = NEGINF; r3[0] = NEGINF;
#pragma unroll
    for (int k = 1; k < 4; ++k) {
        const float* r = base + (size_t)(T_DIM - k) * C_DIM;
        rb[k] = r[0]; r1[k] = r[lab1]; r3[k] = r[lab3];
    }
#pragma unroll
    for (int k = 0; k < 4; ++k) {
        if (st) {
            ra1[k] = Ab[(size_t)(T_DIM - 1 - k) * U_DIM + u1];
            ra3[k] = Ab[(size_t)(T_DIM - 1 - k) * U_DIM + u3];
        } else { ra1[k] = NEGINF; ra3[k] = NEGINF; }
    }
    for (int ob = 0; ob < T_DIM; ob += 4) {
#pragma unroll
        for (int k = 0; k < 4; ++k) {
            const int t = T_DIM - 1 - ob - k;
            float ph0 = v0 ? rb[k] : NEGINF;
            float ph1 = v1 ? r1[k] : NEGINF;
            float ph2 = v2 ? rb[k] : NEGINF;
            float ph3 = v3 ? r3[k] : NEGINF;
            float a1v = ra1[k], a3v = ra3[k];
            if (t - 3 >= 1) {
                const float* r = base + (size_t)(t - 3) * C_DIM;
                rb[k] = r[0]; r1[k] = r[lab1]; r3[k] = r[lab3];
            }
            if (t - 4 >= 0 && st) {
                ra1[k] = Ab[(size_t)(t - 4) * U_DIM + u1];
                ra3[k] = Ab[(size_t)(t - 4) * U_DIM + u3];
            }
            float q0 = ph0 + b0, q1 = ph1 + b1, q2 = ph2 + b2, q3 = ph3 + b3;
            float qd0 = __shfl_down(q0, 1, 64);
            float qd1 = __shfl_down(q1, 1, 64);
            if (L == 63) { qd0 = NEGINF; qd1 = NEGINF; }
            float n0 = lse2f(q0, q1);
            float n1 = lse3f(q1, q2, skipA ? q3 : NEGINF);
            float n2 = lse2f(q2, q3);
            float n3 = lse3f(q3, qd0, skipB ? qd1 : NEGINF);
            bool fin = (t == hl - 1);
            b0 = fin ? f0 : n0;
            b1 = fin ? f1 : n1;
            b2 = fin ? f2 : n2;
            b3 = fin ? f3 : n3;
            if (st) {
                float risk = 0.1f * (float)t * inv_hl;
                float bl1 = (a1v == NEGINF) ? NEGINF : b1;
                float bp1 = log_sub_expf(bl1, prev1 + ph1);
                float x1 = a1v + bp1 - risk;
                if (x1 != NEGINF) {
                    float nm = fmaxf(m1, x1);
                    ss1 = ss1 * __expf(m1 - nm) + __expf(x1 - nm);
                    m1 = nm;
                }
                prev1 = bl1;
                float bl3 = (a3v == NEGINF) ? NEGINF : b3;
                float bp3 = log_sub_expf(bl3, prev3 + ph3);
                float x3 = a3v + bp3 - risk;
                if (x3 != NEGINF) {
                    float nm = fmaxf(m3, x3);
                    ss3 = ss3 * __expf(m3 - nm) + __expf(x3 - nm);
                    m3 = nm;
                }
                prev3 = bl3;
            }
        }
    }
    __shared__ float shlu[U_DIM];
    if (st) {
        shlu[u1] = (m1 == NEGINF) ? NEGINF : (m1 + __logf(ss1));
        shlu[u3] = (m3 == NEGINF) ? NEGINF : (m3 + __logf(ss3));
    }
    __syncthreads();
    if (threadIdx.x == 0) {
        int cnt = 0;
        for (int u = 0; u < U_DIM; ++u) cnt += (shlu[u] != NEGINF) ? 1 : 0;
        int last = cnt - 1;
        last = last < 0 ? 0 : (last > U_DIM - 1 ? U_DIM - 1 : last);
        out[b] = -shlu[last];
    }
}

extern "C" void kernel_launch(void* const* d_in, const int* in_sizes, int n_in,
                              void* d_out, int out_size, void* d_ws, size_t ws_size,
                              hipStream_t stream) {
    const float* nnet  = (const float*)d_in[0];
    const int*   ys    = (const int*)d_in[1];
    const int*   hlens = (const int*)d_in[2];
    const int*   ylens = (const int*)d_in[3];
    float*       outp  = (float*)d_out;
    const int B = in_sizes[2];
    const size_t TP = T_DIM + 2 * PAD;
    const size_t szP  = (size_t)B * TP * U_DIM;
    const size_t szPB = (size_t)B * TP;
    const size_t szA  = (size_t)B * AROWS * U_DIM;
    const size_t need = (szP + szPB + 2 * szA) * sizeof(float);

    if (ws_size >= need) {
        float* P    = (float*)d_ws;
        float* PB   = P + szP;
        float* A    = PB + szPB;
        float* Braw = A + szA;
        brctc_gather<<<dim3(T_DIM, B), 128, 0, stream>>>(nnet, ys, P, PB);
        brctc_fused<<<B, 256, 0, stream>>>(P, PB, ys, hlens, ylens, A, Braw, outp);
    } else {
        float* A = (float*)d_ws;
        brctc_fwd64<<<B, 64, 0, stream>>>(nnet, ys, hlens, ylens, A);
        brctc_bwd64<<<B, 64, 0, stream>>>(nnet, ys, hlens, ylens, A, outp);
    }
}